// Round 2
// baseline (349.345 us; speedup 1.0000x reference)
//
#include <hip/hip_runtime.h>
#include <hip/hip_bf16.h>
#include <cstdint>

#define N_ATOMS 100000
#define NFEAT   256
#define NMOL    1024
#define MP      100096   // 782 * 128
#define MTILES  782

static constexpr float SCALE_C = 5.992277830325989f;
static constexpr float SHIFT_C = -406274.63784969115f;

typedef __attribute__((ext_vector_type(8))) short short8;    // bf16x8 MFMA operand
typedef __attribute__((ext_vector_type(4))) float float4_t;  // f32x4 accumulator

__device__ __forceinline__ unsigned short f2bf(float x) {
    union { float f; uint32_t u; } v; v.f = x;
    uint32_t r = (v.u + 0x7fffu + ((v.u >> 16) & 1u)) >> 16;
    return (unsigned short)r;
}

__device__ __forceinline__ float silu(float x) {
    return x / (1.0f + __expf(-x));
}

// async global->LDS, 16B/lane; LDS dest wave-uniform, lane i lands at +i*16B
__device__ __forceinline__ void async16(void* lds, const void* g) {
    __builtin_amdgcn_global_load_lds(
        (const __attribute__((address_space(1))) unsigned int*)(uintptr_t)g,
        (__attribute__((address_space(3))) unsigned int*)(uint32_t)(uintptr_t)lds,
        16, 0, 0);
}

// Swizzled LDS fragment read: buf is [128 rows][128 k] bf16, 16B chunks
// XOR-permuted per row: physical chunk = c ^ (r & 15). Conflict-free b128.
__device__ __forceinline__ short8 read8(const unsigned short* buf, int r, int c) {
    return *(const short8*)&buf[r * 128 + (((c ^ (r & 15)) & 15) << 3)];
}

// ---------------------------------------------------------------------------
// Prep: W1,W2 fp32 [k][n] -> bf16 "transposed + swizzled" images:
//   Ws[n*256 + (k>>7)*128 + ((((k>>3)&15) ^ (n&15))<<3) + (k&7)] = bf16(W[k][n])
// so that async16 staging of a [n][k-half] tile is a LINEAR 1KB/wave read and
// the LDS image is already XOR-swizzled. Also init out[] = SHIFT.
// ---------------------------------------------------------------------------
__global__ void prep(const float* __restrict__ W1, const float* __restrict__ W2,
                     unsigned short* __restrict__ W1s, unsigned short* __restrict__ W2s,
                     float* __restrict__ out) {
    int g = blockIdx.x * 256 + threadIdx.x;          // 0 .. 131071
    const float* W = (g < 65536) ? W1 : W2;
    unsigned short* Ws = (g < 65536) ? W1s : W2s;
    int idx = g & 65535;
    int k = idx >> 8, n = idx & 255;
    int kc = (k >> 3) & 15;
    int pos = n * 256 + ((k >> 7) << 7) + (((kc ^ (n & 15)) & 15) << 3) + (k & 7);
    Ws[pos] = f2bf(W[idx]);
    if (g < NMOL) out[g] = SHIFT_C;
}

// ---------------------------------------------------------------------------
// 128x128 tile GEMM over K=256 in two K=128 halves (2 barriers/half-pair).
// MODE 0 (layer 1): A = atom_node fp32 (manual stage + cvt), W = W1s.
//   Computes D = W1^T · A^T (operand-swapped MFMA) so each lane's C-frag is
//   4 k-consecutive H1 values -> direct swizzled 8B stores to H1g, no LDS
//   transpose. H1g ends up in the same swizzled layout as W1s/W2s.
// MODE 1 (layer 2+3+pool): A = H1g bf16 (async stage), W = W2s. Natural
//   orientation; epilogue: silu, dot W3, lane-reduce, atomicAdd per atom.
// ---------------------------------------------------------------------------
template <int MODE>
__global__ __launch_bounds__(256, 2)
void gemm(const void* __restrict__ Ag, const unsigned short* __restrict__ Wg,
          const float* __restrict__ bias, unsigned short* __restrict__ H1g,
          const float* __restrict__ W3, const float* __restrict__ b3,
          const int* __restrict__ batch, float* __restrict__ out) {
    __shared__ unsigned short As[128 * 128];   // 32 KB
    __shared__ unsigned short Bs[128 * 128];   // 32 KB

    const int tid = threadIdx.x;
    const int wv = tid >> 6, lane = tid & 63;
    const int fl = lane & 15, qd = lane >> 4;
    const int m0 = blockIdx.x * 128;
    const int by = blockIdx.y;
    const int n0 = by * 128;
    const int offA = (wv >> 1) * 64;   // A-operand-side wave offset
    const int offB = (wv & 1) * 64;    // B-operand-side wave offset

    float4_t acc[4][4] = {};

    for (int h = 0; h < 2; ++h) {
        // ---- stage W tile (always async, source pre-swizzled) ----
        {
            const unsigned short* src = Wg + (size_t)n0 * 256 + h * 128;
#pragma unroll
            for (int i = 0; i < 8; ++i) {
                int rb = wv * 32 + i * 4;
                async16(&Bs[rb * 128], src + (size_t)rb * 256 + lane * 8);
            }
        }
        // ---- stage A tile ----
        if (MODE == 0) {
            const float* Af = (const float*)Ag;
#pragma unroll
            for (int it = 0; it < 8; ++it) {
                int r = it * 16 + (tid >> 4);
                int col = (tid & 15) * 8;
                int grow = m0 + r;
                float4 v0 = {0.f, 0.f, 0.f, 0.f}, v1 = {0.f, 0.f, 0.f, 0.f};
                if (grow < N_ATOMS) {
                    const float* p = Af + (size_t)grow * 256 + h * 128 + col;
                    v0 = *(const float4*)p;
                    v1 = *(const float4*)(p + 4);
                }
                short8 o;
                o[0] = f2bf(v0.x); o[1] = f2bf(v0.y); o[2] = f2bf(v0.z); o[3] = f2bf(v0.w);
                o[4] = f2bf(v1.x); o[5] = f2bf(v1.y); o[6] = f2bf(v1.z); o[7] = f2bf(v1.w);
                int c = col >> 3;
                *(short8*)&As[r * 128 + (((c ^ (r & 15)) & 15) << 3)] = o;
            }
        } else {
            const unsigned short* src = (const unsigned short*)Ag + (size_t)m0 * 256 + h * 128;
#pragma unroll
            for (int i = 0; i < 8; ++i) {
                int rb = wv * 32 + i * 4;
                async16(&As[rb * 128], src + (size_t)rb * 256 + lane * 8);
            }
        }
        __syncthreads();

        const unsigned short* bufA = (MODE == 0) ? Bs : As;  // A-operand source
        const unsigned short* bufB = (MODE == 0) ? As : Bs;  // B-operand source
#pragma unroll
        for (int kc = 0; kc < 4; ++kc) {
            short8 fa[4], fb[4];
#pragma unroll
            for (int i = 0; i < 4; ++i)
                fa[i] = read8(bufA, offA + i * 16 + fl, kc * 4 + qd);
#pragma unroll
            for (int j = 0; j < 4; ++j)
                fb[j] = read8(bufB, offB + j * 16 + fl, kc * 4 + qd);
#pragma unroll
            for (int i = 0; i < 4; ++i)
#pragma unroll
                for (int j = 0; j < 4; ++j)
                    acc[i][j] = __builtin_amdgcn_mfma_f32_16x16x32_bf16(
                        fa[i], fb[j], acc[i][j], 0, 0, 0);
        }
        __syncthreads();
    }

    if (MODE == 0) {
        // acc[i][j] = H1[atom = m0+offB+j*16+fl][n = n0+offA+i*16+qd*4+r]
#pragma unroll
        for (int i = 0; i < 4; ++i) {
            int nb = offA + i * 16 + qd * 4;          // n base within 128
            float4 b4 = *(const float4*)&bias[n0 + nb];
            int c = nb >> 3, ob = nb & 7;
#pragma unroll
            for (int j = 0; j < 4; ++j) {
                int atom = m0 + offB + j * 16 + fl;
                if (atom < N_ATOMS) {
                    ushort4 o;
                    o.x = f2bf(silu(acc[i][j][0] + b4.x));
                    o.y = f2bf(silu(acc[i][j][1] + b4.y));
                    o.z = f2bf(silu(acc[i][j][2] + b4.z));
                    o.w = f2bf(silu(acc[i][j][3] + b4.w));
                    *(ushort4*)&H1g[(size_t)atom * 256 + n0 +
                                    (((c ^ (atom & 15)) & 15) << 3) + ob] = o;
                }
            }
        }
    } else {
        // acc[i][j] = H2pre[atom = m0+offA+i*16+qd*4+r][col = n0+offB+j*16+fl]
        float rs[4][4] = {};
#pragma unroll
        for (int j = 0; j < 4; ++j) {
            int col = n0 + offB + j * 16 + fl;
            float b = bias[col];
            float w3 = W3[col];
#pragma unroll
            for (int i = 0; i < 4; ++i)
#pragma unroll
                for (int r = 0; r < 4; ++r)
                    rs[i][r] += silu(acc[i][j][r] + b) * w3;
        }
#pragma unroll
        for (int i = 0; i < 4; ++i)
#pragma unroll
            for (int r = 0; r < 4; ++r) {
                float v = rs[i][r];
                v += __shfl_xor(v, 1);
                v += __shfl_xor(v, 2);
                v += __shfl_xor(v, 4);
                v += __shfl_xor(v, 8);
                rs[i][r] = v;
            }
        float* red = (float*)As;   // safe: loop ended with __syncthreads
        if (fl == 0) {
#pragma unroll
            for (int i = 0; i < 4; ++i)
#pragma unroll
                for (int r = 0; r < 4; ++r)
                    red[(offA + i * 16 + qd * 4 + r) * 2 + (wv & 1)] = rs[i][r];
        }
        __syncthreads();
        if (tid < 128) {
            int atom = m0 + tid;
            if (atom < N_ATOMS) {
                float v = red[tid * 2] + red[tid * 2 + 1];
                if (by == 0) v += b3[0];
                atomicAdd(&out[batch[atom]], v * SCALE_C);
            }
        }
    }
}

// ---------------------------------------------------------------------------
extern "C" void kernel_launch(void* const* d_in, const int* in_sizes, int n_in,
                              void* d_out, int out_size, void* d_ws, size_t ws_size,
                              hipStream_t stream) {
    const float* A     = (const float*)d_in[0];
    const int*   batch = (const int*)d_in[1];
    const float* W1    = (const float*)d_in[2];
    const float* b1    = (const float*)d_in[3];
    const float* W2    = (const float*)d_in[4];
    const float* b2    = (const float*)d_in[5];
    const float* W3    = (const float*)d_in[6];
    const float* b3    = (const float*)d_in[7];
    float* out = (float*)d_out;

    unsigned short* H1g = (unsigned short*)d_ws;          // MP*256 bf16 (swizzled)
    unsigned short* W1s = H1g + (size_t)MP * NFEAT;       // 256*256 bf16 (swizzled)
    unsigned short* W2s = W1s + 65536;

    prep<<<dim3(512), 256, 0, stream>>>(W1, W2, W1s, W2s, out);

    // layer 1: H1g = silu(A @ W1 + b1)  [bf16, swizzled layout]
    gemm<0><<<dim3(MTILES, 2), 256, 0, stream>>>(
        A, W1s, b1, H1g, nullptr, nullptr, nullptr, nullptr);
    // layer 2+3+pool: out[mol] += SCALE * (silu(H1 @ W2 + b2) . W3 + b3)
    gemm<1><<<dim3(MTILES, 2), 256, 0, stream>>>(
        H1g, W2s, b2, nullptr, W3, b3, batch, out);
}